// Round 22
// baseline (197.101 us; speedup 1.0000x reference)
//
#include <hip/hip_runtime.h>

// EnhancedMemoryStack: B=32768, S=16, D=64. fp32 I/O; bf16 MFMA internally.
//
// Algebra:
//   scores = xhat (Q K^T) xhat^T = xhat M xhat^T, with M = Q K^T (128x128) precomputed.
//   z_read = sum_t w[t] vhat[t],  w[t] = sum_s (np[s]/rowsum[s]) e[s][t]  (softmax folded)
//
// R22 = SPLIT STREAM/ATTENTION (last structural hypothesis):
//   Fused kernel (R21, 145us) is BW-SERVICE-limited: 3.0 TB/s achieved vs 6.3-7.0
//   for clean streams on the same device; compute pipes ~10% busy. Split:
//   K1 ems_lerp: pure streaming lerp (copy-shaped, huge occupancy) -> copy rate.
//   K2 ems_attn: R21 minus lerp/store; reads mem_new JUST WRITTEN by K1 ->
//   ~95% L3-resident (268MB vs 256MB L3) -> K2 HBM traffic ~30MB, L3-hit latency.
//   Outputs bit-identical to R21 (K1 stores exact fp32 lerp; K2 bf16-converts it).
//
// d_ws: [0..4) counter, [1024..33792) Mt row-major bf16 (ws_size >= 33792).

typedef __bf16 bf16x8 __attribute__((ext_vector_type(8)));
typedef float  f32x4  __attribute__((ext_vector_type(4)));
typedef float  f4     __attribute__((ext_vector_type(4)));

#define B_TOT   32768
#define GRID_WG 512
#define NWAVES  4096
#define BPW     8
#define LOG2E   1.4426950408889634f
#define EXSC    0.18033688011112042f   // 0.125 * log2(e)

__device__ __forceinline__ unsigned short f2bf(float x) {
  __bf16 h = (__bf16)x;
  return __builtin_bit_cast(unsigned short, h);
}
__device__ __forceinline__ float rcp_f(float x) { return __builtin_amdgcn_rcpf(x); }
__device__ __forceinline__ float ex2_f(float x) { return __builtin_amdgcn_exp2f(x); }
__device__ __forceinline__ float sigm(float x) { return rcp_f(1.0f + ex2_f(-LOG2E * x)); }

// exact bf16x8 negation: flip sign bits (== (__bf16)(-x) under RNE)
__device__ __forceinline__ bf16x8 negbf8(bf16x8 v) {
  uint4 u = __builtin_bit_cast(uint4, v);
  u.x ^= 0x80008000u; u.y ^= 0x80008000u; u.z ^= 0x80008000u; u.w ^= 0x80008000u;
  return __builtin_bit_cast(bf16x8, u);
}

// 16-lane (row) sum, bit-identical to shfl_xor 1,2,4,8 tree, all VALU via DPP.
__device__ __forceinline__ float dpp_sum16(float v) {
  int x;
  x = __builtin_amdgcn_update_dpp(0, __builtin_bit_cast(int, v), 0xB1, 0xF, 0xF, false);  // quad_perm xor1
  v += __builtin_bit_cast(float, x);
  x = __builtin_amdgcn_update_dpp(0, __builtin_bit_cast(int, v), 0x4E, 0xF, 0xF, false);  // quad_perm xor2
  v += __builtin_bit_cast(float, x);
  x = __builtin_amdgcn_update_dpp(0, __builtin_bit_cast(int, v), 0x141, 0xF, 0xF, false); // row_half_mirror
  v += __builtin_bit_cast(float, x);
  x = __builtin_amdgcn_update_dpp(0, __builtin_bit_cast(int, v), 0x140, 0xF, 0xF, false); // row_mirror
  v += __builtin_bit_cast(float, x);
  return v;
}

// row_ror:N (wrapping shift-right within each 16-lane row): dst[i] = src[(i-N)&15]
__device__ __forceinline__ float dpp_ror1(float v) {   // dst[i] = src[(i-1)&15]
  int x = __builtin_amdgcn_update_dpp(0, __builtin_bit_cast(int, v), 0x121, 0xF, 0xF, true);
  return __builtin_bit_cast(float, x);
}
__device__ __forceinline__ float dpp_ror15(float v) {  // dst[i] = src[(i+1)&15]
  int x = __builtin_amdgcn_update_dpp(0, __builtin_bit_cast(int, v), 0x12F, 0xF, 0xF, true);
  return __builtin_bit_cast(float, x);
}

__global__ void ems_fin(const unsigned int* __restrict__ c, float* __restrict__ out) {
  if (threadIdx.x == 0) out[0] = (float)(*c) * (1.0f / 32768.0f);
}

// Mt[e2][e] = sum_{E'} Q[e][E'] K[e2][E']; also zeroes the active-slot counter.
__global__ void __launch_bounds__(128)
ems_mt(const float* __restrict__ wqr, const float* __restrict__ wqi,
       const float* __restrict__ wkr, const float* __restrict__ wki,
       unsigned short* __restrict__ mt, unsigned int* __restrict__ cnt)
{
  if (blockIdx.x == 0 && threadIdx.x == 0) *cnt = 0u;
  __shared__ float sK[128];
  const int e2 = (int)blockIdx.x;
  const int e  = (int)threadIdx.x;
  float kv;
  if (e < 64) kv = (e2 < 64) ? wkr[e*64 + e2]      : -wki[e*64 + (e2-64)];
  else        kv = (e2 < 64) ? wki[(e-64)*64 + e2] :  wkr[(e-64)*64 + (e2-64)];
  sK[e] = kv;
  __syncthreads();
  float acc = 0.0f;
  #pragma unroll 8
  for (int Ep = 0; Ep < 64; ++Ep) {
    float q = (e < 64) ? wqr[Ep*64 + e] : -wqi[Ep*64 + (e-64)];
    acc += q * sK[Ep];
  }
  #pragma unroll 8
  for (int Ep = 0; Ep < 64; ++Ep) {
    float q = (e < 64) ? wqi[Ep*64 + e] : wqr[Ep*64 + (e-64)];
    acc += q * sK[64 + Ep];
  }
  mt[e2*128 + e] = f2bf(acc);
}

// K1: pure streaming lerp. mem_new = mem*(1-pu) + pu*z_flat. Copy-shaped.
// Each wave's 64 consecutive f4 (1KB) lie within one batch (8KB) -> b wave-uniform.
__global__ void __launch_bounds__(256)
ems_lerp(const float* __restrict__ z_real, const float* __restrict__ z_imag,
         const float* __restrict__ mem,    const float* __restrict__ ctrl,
         float* __restrict__ out_mem)
{
  const f4* mem4 = (const f4*)mem;
  const f4* zr4  = (const f4*)z_real;
  const f4* zi4  = (const f4*)z_imag;
  f4* omem4 = (f4*)out_mem;

  const int stride = 2048 * 256;                  // f4 per grid pass
  int i4 = (int)blockIdx.x * 256 + (int)threadIdx.x;
  #pragma unroll 1
  for (; i4 < B_TOT * 512; i4 += stride) {
    const int b = __builtin_amdgcn_readfirstlane(i4 >> 9);   // wave-uniform batch
    float pu = sigm(ctrl[b*3+0]);
    float po = sigm(ctrl[b*3+1]);
    float st = sigm(ctrl[b*3+2]);
    float rt = rcp_f(pu + po + st + 1e-6f);
    pu *= rt;
    const int q = i4 & 511, col4 = q & 31;
    f4 z4 = (col4 < 16) ? zr4[b*16 + col4] : zi4[b*16 + (col4 - 16)];  // L1/L2-hot
    f4 r = mem4[i4] * (1.0f - pu) + pu * z4;
    omem4[i4] = r;
  }
}

// K2: attention over mem_new (L3-hot). R21 structure minus lerp/global-store.
__global__ void __launch_bounds__(512, 4)
ems_attn(const float* __restrict__ nmem,   const float* __restrict__ ptrv,
         const float* __restrict__ ctrl,
         const float* __restrict__ wvr,    const float* __restrict__ wvi,
         const unsigned short* __restrict__ mt,
         float* __restrict__ out_zr, float* __restrict__ out_zi,
         float* __restrict__ out_ptr, unsigned int* __restrict__ ws_cnt)
{
  // [0..16384)     Mt bf16 [e2=128][e=128], 16B-chunk swizzle: chunk ^ (e2&15)
  // [16384..24576) Wv_r, Wv_i bf16 [e][d], 16B-chunk ^ (e&7)
  // [24576..40960) per-wave 4KB buffer: xhat staging [16][128] (chunk^row), then SY
  __shared__ __align__(16) unsigned short lds[40960];

  const int tid = (int)threadIdx.x;

  for (int idx = tid; idx < 16384; idx += 512) {
    int e2 = idx >> 7, e = idx & 127;
    lds[(e2 << 7) + (((e >> 3) ^ (e2 & 15)) << 3) + (e & 7)] = mt[idx];
  }
  #pragma unroll
  for (int m = 0; m < 2; ++m) {
    const float* wp = m ? wvi : wvr;
    for (int idx = tid; idx < 4096; idx += 512) {
      int e = idx >> 6, d = idx & 63;
      lds[16384 + (m << 12) + (e << 6) + (((d >> 3) ^ (e & 7)) << 3) + (d & 7)] = f2bf(wp[idx]);
    }
  }
  __syncthreads();

  const int lane = tid & 63;
  const int wv   = tid >> 6;
  const int c    = lane & 15;   // MFMA A/B index; also slot s for S^T rows
  const int g    = lane >> 4;   // k-chunk group / C-row group
  const int d4   = lane & 31;

  // ---- phase stagger: 16 distinct phases per CU ----
  {
    int phase = (wv << 1) | (((int)blockIdx.x >> 8) & 1);
    #pragma unroll 1
    for (int i = 0; i < phase; ++i) __builtin_amdgcn_s_sleep(44);
  }

  unsigned short* SY = &lds[24576 + (wv << 11)];   // 4KB: xhat staging, then SY

  const f4* nmem4 = (const f4*)nmem;

  unsigned int active_acc = 0u;
  const int b0 = (int)blockIdx.x * 8 + wv;

  for (int it = 0; it < BPW; ++it) {
    const int b = b0 + it * NWAVES;
    const int bu = __builtin_amdgcn_readfirstlane(b);

    // ---------- COALESCED loads of mem_new (L3-hot) + ptr ----------
    f4 cm[8];
    #pragma unroll
    for (int k = 0; k < 8; ++k) cm[k] = nmem4[b*512 + (k << 6) + lane];
    float pc = ptrv[b*16 + c];

    // ---------- gates (s_load path) + pointer update (DPP rotations) ----------
    float pu = sigm(ctrl[bu*3+0]);
    float po = sigm(ctrl[bu*3+1]);
    float st = sigm(ctrl[bu*3+2]);
    float rt = rcp_f(pu + po + st + 1e-6f);
    pu *= rt; po *= rt; st *= rt;

    float pm = dpp_ror1(pc);    // ptr[(c-1)&15]
    float pp = dpp_ror15(pc);   // ptr[(c+1)&15]
    float np = pu*pm + po*pp + st*pc;
    if (g == 0) out_ptr[b*16 + c] = np;
    unsigned long long ball = __ballot(np > 0.1f);
    active_acc += (unsigned int)__popcll(ball & 0xFFFFull);

    // ---------- xhat = bf16(mem_new) -> LDS staging ----------
    #pragma unroll
    for (int k = 0; k < 8; ++k) {
      f4 r = cm[k];
      uint2 pk;
      pk.x = (unsigned)f2bf(r[0]) | ((unsigned)f2bf(r[1]) << 16);
      pk.y = (unsigned)f2bf(r[2]) | ((unsigned)f2bf(r[3]) << 16);
      int row = (k << 1) + (lane >> 5);
      *(uint2*)&SY[(row << 7) + (((d4 >> 1) ^ row) << 3) + ((d4 & 1) << 2)] = pk;
    }

    // ---------- fragment reads ----------
    bf16x8 af[4], afn[2];
    #pragma unroll
    for (int t = 0; t < 4; ++t)
      af[t] = *(const bf16x8*)&SY[(c << 7) + ((((t << 2) + g) ^ c) << 3)];
    afn[0] = negbf8(af[2]);
    afn[1] = negbf8(af[3]);

    // ---------- y = xhat*M (prio-boosted) ----------
    __builtin_amdgcn_s_setprio(1);
    #pragma unroll
    for (int n2 = 0; n2 < 8; ++n2) {
      int e2 = (n2 << 4) + c;
      f32x4 acc = {0.f,0.f,0.f,0.f};
      #pragma unroll
      for (int T = 0; T < 4; ++T) {
        bf16x8 am = *(const bf16x8*)&lds[(e2 << 7) + ((((T << 2) + g) ^ c) << 3)];
        acc = __builtin_amdgcn_mfma_f32_16x16x32_bf16(am, af[T], acc, 0, 0, 0);
      }
      uint2 pk;
      pk.x = (unsigned)f2bf(acc[0]) | ((unsigned)f2bf(acc[1]) << 16);
      pk.y = (unsigned)f2bf(acc[2]) | ((unsigned)f2bf(acc[3]) << 16);
      *(uint2*)&SY[(c << 7) + ((((n2 << 1) + (g >> 1)) ^ c) << 3) + ((g & 1) << 2)] = pk;
    }

    // ---------- S^T = xhat . y^T ----------
    f32x4 sc = {0.f,0.f,0.f,0.f};
    #pragma unroll
    for (int T = 0; T < 4; ++T) {
      bf16x8 yb = *(const bf16x8*)&SY[(c << 7) + ((((T << 2) + g) ^ c) << 3)];
      sc = __builtin_amdgcn_mfma_f32_16x16x32_bf16(af[T], yb, sc, 0, 0, 0);
    }
    __builtin_amdgcn_s_setprio(0);

    // ---------- fast softmax + fold np ----------
    float e0 = ex2_f(sc[0] * EXSC);
    float e1 = ex2_f(sc[1] * EXSC);
    float e2v = ex2_f(sc[2] * EXSC);
    float e3 = ex2_f(sc[3] * EXSC);
    float r = (e0 + e1) + (e2v + e3);
    r += __shfl_xor(r, 16, 64);
    r += __shfl_xor(r, 32, 64);
    float u = np * rcp_f(r);
    float w4[4];
    w4[0] = dpp_sum16(u * e0);
    w4[1] = dpp_sum16(u * e1);
    w4[2] = dpp_sum16(u * e2v);
    w4[3] = dpp_sum16(u * e3);

    // ---------- vhat (prio-boosted) + weighted readout ----------
    __builtin_amdgcn_s_setprio(1);
    #pragma unroll
    for (int n = 0; n < 4; ++n) {
      int eb = 16384 + (((n << 4) + c) << 6);
      int e7 = c & 7;
      f32x4 ar = {0.f,0.f,0.f,0.f}, ai = {0.f,0.f,0.f,0.f};
      #pragma unroll
      for (int t = 0; t < 2; ++t) {
        int ch = (((t << 2) + g) ^ e7) << 3;
        bf16x8 fr = *(const bf16x8*)&lds[eb + ch];
        bf16x8 fi = *(const bf16x8*)&lds[eb + 4096 + ch];
        ar = __builtin_amdgcn_mfma_f32_16x16x32_bf16(af[t],   fr, ar, 0,0,0);
        ai = __builtin_amdgcn_mfma_f32_16x16x32_bf16(af[t],   fi, ai, 0,0,0);
        ar = __builtin_amdgcn_mfma_f32_16x16x32_bf16(afn[t],  fi, ar, 0,0,0);
        ai = __builtin_amdgcn_mfma_f32_16x16x32_bf16(af[t+2], fr, ai, 0,0,0);
      }
      float prr = ar[0]*w4[0] + ar[1]*w4[1] + ar[2]*w4[2] + ar[3]*w4[3];
      float pri = ai[0]*w4[0] + ai[1]*w4[1] + ai[2]*w4[2] + ai[3]*w4[3];
      prr += __shfl_xor(prr, 16, 64);
      prr += __shfl_xor(prr, 32, 64);
      pri += __shfl_xor(pri, 16, 64);
      pri += __shfl_xor(pri, 32, 64);
      if (g == 0) out_zr[b*64 + (n << 4) + c] = prr;
      if (g == 1) out_zi[b*64 + (n << 4) + c] = pri;
    }
    __builtin_amdgcn_s_setprio(0);
  }

  // ---------- per-WG reduction of active-slot count, 1 atomic per WG ----------
  __syncthreads();
  unsigned int* cnt_lds = (unsigned int*)&lds[24576];
  if (tid == 0) *cnt_lds = 0u;
  __syncthreads();
  if (lane == 0) atomicAdd(cnt_lds, active_acc);
  __syncthreads();
  if (tid == 0) atomicAdd(ws_cnt, *cnt_lds);
}

extern "C" void kernel_launch(void* const* d_in, const int* in_sizes, int n_in,
                              void* d_out, int out_size, void* d_ws, size_t ws_size,
                              hipStream_t stream) {
  const float* z_real = (const float*)d_in[0];
  const float* z_imag = (const float*)d_in[1];
  const float* memp   = (const float*)d_in[2];
  const float* ptrv   = (const float*)d_in[3];
  const float* ctrl   = (const float*)d_in[4];
  const float* wq_r   = (const float*)d_in[5];
  const float* wq_i   = (const float*)d_in[6];
  const float* wk_r   = (const float*)d_in[7];
  const float* wk_i   = (const float*)d_in[8];
  const float* wv_r   = (const float*)d_in[9];
  const float* wv_i   = (const float*)d_in[10];

  float* out     = (float*)d_out;
  float* out_zr  = out;
  float* out_zi  = out + 2097152;
  float* out_mem = out + 4194304;
  float* out_ptr = out + 71303168;
  float* out_sc  = out + 71827456;

  unsigned int*   cnt = (unsigned int*)d_ws;
  unsigned short* mtp = (unsigned short*)((char*)d_ws + 1024);  // ws_size >= 33792

  ems_mt<<<128, 128, 0, stream>>>(wq_r, wq_i, wk_r, wk_i, mtp, cnt);
  ems_lerp<<<2048, 256, 0, stream>>>(z_real, z_imag, memp, ctrl, out_mem);
  ems_attn<<<GRID_WG, 512, 0, stream>>>(out_mem, ptrv, ctrl,
                                        wv_r, wv_i, mtp,
                                        out_zr, out_zi, out_ptr, cnt);
  ems_fin<<<1, 64, 0, stream>>>(cnt, out_sc);
}

// Round 23
// 144.833 us; speedup vs baseline: 1.3609x; 1.3609x over previous
//
#include <hip/hip_runtime.h>

// EnhancedMemoryStack: B=32768, S=16, D=64. fp32 I/O; bf16 MFMA internally.
//
// FINAL (R23 = R21, session best 145.09us, locked in after R22's split regressed):
//   scores = xhat (Q K^T) xhat^T = xhat M xhat^T, M = Q K^T (128x128) precomputed.
//   z_read = sum_t w[t] vhat[t],  w[t] = sum_s (np[s]/rowsum[s]) e[s][t]  (softmax folded)
// Techniques: fused single-pass over mem (268MB in / 268MB out), coalesced staging
// via LDS roundtrip, yT-direction MFMA, S^T operand-swap softmax (np lane-local),
// fast exp2/rcp, DPP reduction trees, 16-phase wave stagger, s_setprio on MFMA
// clusters, scalarized ctrl loads, DPP ptr rotations.
//
// 512-thr WG (8 waves): LDS = M(32K)+Wv(16K)+8x4K = 80KB -> 2 WG/CU.
// d_ws: [0..4) counter, [1024..33792) Mt row-major bf16 (ws_size >= 33792).

typedef __bf16 bf16x8 __attribute__((ext_vector_type(8)));
typedef float  f32x4  __attribute__((ext_vector_type(4)));
typedef float  f4     __attribute__((ext_vector_type(4)));

#define B_TOT   32768
#define GRID_WG 512
#define NWAVES  4096
#define BPW     8
#define LOG2E   1.4426950408889634f
#define EXSC    0.18033688011112042f   // 0.125 * log2(e)

__device__ __forceinline__ unsigned short f2bf(float x) {
  __bf16 h = (__bf16)x;
  return __builtin_bit_cast(unsigned short, h);
}
__device__ __forceinline__ float rcp_f(float x) { return __builtin_amdgcn_rcpf(x); }
__device__ __forceinline__ float ex2_f(float x) { return __builtin_amdgcn_exp2f(x); }
__device__ __forceinline__ float sigm(float x) { return rcp_f(1.0f + ex2_f(-LOG2E * x)); }

// exact bf16x8 negation: flip sign bits (== (__bf16)(-x) under RNE)
__device__ __forceinline__ bf16x8 negbf8(bf16x8 v) {
  uint4 u = __builtin_bit_cast(uint4, v);
  u.x ^= 0x80008000u; u.y ^= 0x80008000u; u.z ^= 0x80008000u; u.w ^= 0x80008000u;
  return __builtin_bit_cast(bf16x8, u);
}

// 16-lane (row) sum, bit-identical to shfl_xor 1,2,4,8 tree, all VALU via DPP.
__device__ __forceinline__ float dpp_sum16(float v) {
  int x;
  x = __builtin_amdgcn_update_dpp(0, __builtin_bit_cast(int, v), 0xB1, 0xF, 0xF, false);  // quad_perm xor1
  v += __builtin_bit_cast(float, x);
  x = __builtin_amdgcn_update_dpp(0, __builtin_bit_cast(int, v), 0x4E, 0xF, 0xF, false);  // quad_perm xor2
  v += __builtin_bit_cast(float, x);
  x = __builtin_amdgcn_update_dpp(0, __builtin_bit_cast(int, v), 0x141, 0xF, 0xF, false); // row_half_mirror
  v += __builtin_bit_cast(float, x);
  x = __builtin_amdgcn_update_dpp(0, __builtin_bit_cast(int, v), 0x140, 0xF, 0xF, false); // row_mirror
  v += __builtin_bit_cast(float, x);
  return v;
}

// row_ror:N (wrapping shift-right within each 16-lane row): dst[i] = src[(i-N)&15]
__device__ __forceinline__ float dpp_ror1(float v) {   // dst[i] = src[(i-1)&15]
  int x = __builtin_amdgcn_update_dpp(0, __builtin_bit_cast(int, v), 0x121, 0xF, 0xF, true);
  return __builtin_bit_cast(float, x);
}
__device__ __forceinline__ float dpp_ror15(float v) {  // dst[i] = src[(i+1)&15]
  int x = __builtin_amdgcn_update_dpp(0, __builtin_bit_cast(int, v), 0x12F, 0xF, 0xF, true);
  return __builtin_bit_cast(float, x);
}

__global__ void ems_fin(const unsigned int* __restrict__ c, float* __restrict__ out) {
  if (threadIdx.x == 0) out[0] = (float)(*c) * (1.0f / 32768.0f);
}

// Mt[e2][e] = sum_{E'} Q[e][E'] K[e2][E']; also zeroes the active-slot counter.
__global__ void __launch_bounds__(128)
ems_mt(const float* __restrict__ wqr, const float* __restrict__ wqi,
       const float* __restrict__ wkr, const float* __restrict__ wki,
       unsigned short* __restrict__ mt, unsigned int* __restrict__ cnt)
{
  if (blockIdx.x == 0 && threadIdx.x == 0) *cnt = 0u;
  __shared__ float sK[128];
  const int e2 = (int)blockIdx.x;
  const int e  = (int)threadIdx.x;
  float kv;
  if (e < 64) kv = (e2 < 64) ? wkr[e*64 + e2]      : -wki[e*64 + (e2-64)];
  else        kv = (e2 < 64) ? wki[(e-64)*64 + e2] :  wkr[(e-64)*64 + (e2-64)];
  sK[e] = kv;
  __syncthreads();
  float acc = 0.0f;
  #pragma unroll 8
  for (int Ep = 0; Ep < 64; ++Ep) {
    float q = (e < 64) ? wqr[Ep*64 + e] : -wqi[Ep*64 + (e-64)];
    acc += q * sK[Ep];
  }
  #pragma unroll 8
  for (int Ep = 0; Ep < 64; ++Ep) {
    float q = (e < 64) ? wqi[Ep*64 + e] : wqr[Ep*64 + (e-64)];
    acc += q * sK[64 + Ep];
  }
  mt[e2*128 + e] = f2bf(acc);
}

__global__ void __launch_bounds__(512, 4)
ems_main(const float* __restrict__ z_real, const float* __restrict__ z_imag,
         const float* __restrict__ mem,    const float* __restrict__ ptrv,
         const float* __restrict__ ctrl,
         const float* __restrict__ wvr,    const float* __restrict__ wvi,
         const unsigned short* __restrict__ mt,
         float* __restrict__ out_zr, float* __restrict__ out_zi,
         float* __restrict__ out_mem, float* __restrict__ out_ptr,
         unsigned int* __restrict__ ws_cnt)
{
  // [0..16384)     Mt bf16 [e2=128][e=128], 16B-chunk swizzle: chunk ^ (e2&15)
  // [16384..24576) Wv_r, Wv_i bf16 [e][d], 16B-chunk ^ (e&7)
  // [24576..40960) per-wave 4KB buffer: xhat staging [16][128] (chunk^row), then SY
  __shared__ __align__(16) unsigned short lds[40960];

  const int tid = (int)threadIdx.x;

  for (int idx = tid; idx < 16384; idx += 512) {
    int e2 = idx >> 7, e = idx & 127;
    lds[(e2 << 7) + (((e >> 3) ^ (e2 & 15)) << 3) + (e & 7)] = mt[idx];
  }
  #pragma unroll
  for (int m = 0; m < 2; ++m) {
    const float* wp = m ? wvi : wvr;
    for (int idx = tid; idx < 4096; idx += 512) {
      int e = idx >> 6, d = idx & 63;
      lds[16384 + (m << 12) + (e << 6) + (((d >> 3) ^ (e & 7)) << 3) + (d & 7)] = f2bf(wp[idx]);
    }
  }
  __syncthreads();

  const int lane = tid & 63;
  const int wv   = tid >> 6;
  const int c    = lane & 15;   // MFMA A/B index; also slot s for S^T rows
  const int g    = lane >> 4;   // k-chunk group / C-row group
  const int d4   = lane & 31;   // coalesced staging: float4-column index

  // ---- phase stagger: 16 distinct phases per CU (wv x co-resident-WG parity) ----
  {
    int phase = (wv << 1) | (((int)blockIdx.x >> 8) & 1);
    #pragma unroll 1
    for (int i = 0; i < phase; ++i) __builtin_amdgcn_s_sleep(44);
  }

  unsigned short* SY = &lds[24576 + (wv << 11)];   // 4KB: xhat staging, then SY

  const f4* mem4 = (const f4*)mem;
  const f4* zr4  = (const f4*)z_real;
  const f4* zi4  = (const f4*)z_imag;
  f4* omem4 = (f4*)out_mem;

  unsigned int active_acc = 0u;
  const int b0 = (int)blockIdx.x * 8 + wv;

  for (int it = 0; it < BPW; ++it) {
    const int b = b0 + it * NWAVES;
    const int bu = __builtin_amdgcn_readfirstlane(b);   // wave-uniform -> s_load for ctrl

    // ---------- COALESCED global loads: 8 x 1KB contiguous + 1 z float4 + 1 ptr ----------
    f4 cm[8];
    #pragma unroll
    for (int k = 0; k < 8; ++k) cm[k] = mem4[b*512 + (k << 6) + lane];
    f4 z4 = (d4 < 16) ? zr4[b*16 + d4] : zi4[b*16 + (d4 - 16)];  // serves all k
    float pc = ptrv[b*16 + c];                                    // single ptr load

    // ---------- gates (scalar s_load path) + pointer update (DPP rotations) ----------
    float pu = sigm(ctrl[bu*3+0]);
    float po = sigm(ctrl[bu*3+1]);
    float st = sigm(ctrl[bu*3+2]);
    float rt = rcp_f(pu + po + st + 1e-6f);
    pu *= rt; po *= rt; st *= rt;

    float pm = dpp_ror1(pc);    // ptr[(c-1)&15]  (row_ror:1  = wrapping shift-right)
    float pp = dpp_ror15(pc);   // ptr[(c+1)&15]  (row_ror:15)
    float np = pu*pm + po*pp + st*pc;    // new_ptr for slot s=c
    if (g == 0) out_ptr[b*16 + c] = np;
    unsigned long long ball = __ballot(np > 0.1f);
    active_acc += (unsigned int)__popcll(ball & 0xFFFFull);

    // ---------- lerp (elementwise) + COALESCED store + xhat -> LDS ----------
    float om = 1.0f - pu;
    #pragma unroll
    for (int k = 0; k < 8; ++k) {
      f4 r = cm[k] * om + pu * z4;
      omem4[b*512 + (k << 6) + lane] = r;
      uint2 pk;
      pk.x = (unsigned)f2bf(r[0]) | ((unsigned)f2bf(r[1]) << 16);
      pk.y = (unsigned)f2bf(r[2]) | ((unsigned)f2bf(r[3]) << 16);
      int row = (k << 1) + (lane >> 5);                 // xhat row 0..15
      *(uint2*)&SY[(row << 7) + (((d4 >> 1) ^ row) << 3) + ((d4 & 1) << 2)] = pk;
    }

    // ---------- fragment reads (bit-identical af values) ----------
    bf16x8 af[4], afn[2];
    #pragma unroll
    for (int t = 0; t < 4; ++t)
      af[t] = *(const bf16x8*)&SY[(c << 7) + ((((t << 2) + g) ^ c) << 3)];
    afn[0] = negbf8(af[2]);
    afn[1] = negbf8(af[3]);
    // (xhat buffer now dead; SY writes below reuse it)

    // ---------- y = xhat*M via yT-direction MFMA (prio-boosted cluster) ----------
    __builtin_amdgcn_s_setprio(1);
    #pragma unroll
    for (int n2 = 0; n2 < 8; ++n2) {
      int e2 = (n2 << 4) + c;
      f32x4 acc = {0.f,0.f,0.f,0.f};
      #pragma unroll
      for (int T = 0; T < 4; ++T) {
        bf16x8 am = *(const bf16x8*)&lds[(e2 << 7) + ((((T << 2) + g) ^ c) << 3)];
        acc = __builtin_amdgcn_mfma_f32_16x16x32_bf16(am, af[T], acc, 0, 0, 0);
      }
      uint2 pk;
      pk.x = (unsigned)f2bf(acc[0]) | ((unsigned)f2bf(acc[1]) << 16);
      pk.y = (unsigned)f2bf(acc[2]) | ((unsigned)f2bf(acc[3]) << 16);
      *(uint2*)&SY[(c << 7) + ((((n2 << 1) + (g >> 1)) ^ c) << 3) + ((g & 1) << 2)] = pk;
    }

    // ---------- S^T = xhat . y^T: lane(c,g) holds S[s=c][t=4g+i] ----------
    f32x4 sc = {0.f,0.f,0.f,0.f};
    #pragma unroll
    for (int T = 0; T < 4; ++T) {
      bf16x8 yb = *(const bf16x8*)&SY[(c << 7) + ((((T << 2) + g) ^ c) << 3)];
      sc = __builtin_amdgcn_mfma_f32_16x16x32_bf16(af[T], yb, sc, 0, 0, 0);
    }
    __builtin_amdgcn_s_setprio(0);

    // ---------- fast softmax + fold np: w[t] = sum_s (np[s]/r[s]) e[s][t] ----------
    float e0 = ex2_f(sc[0] * EXSC);
    float e1 = ex2_f(sc[1] * EXSC);
    float e2v = ex2_f(sc[2] * EXSC);
    float e3 = ex2_f(sc[3] * EXSC);
    float r = (e0 + e1) + (e2v + e3);
    r += __shfl_xor(r, 16, 64);
    r += __shfl_xor(r, 32, 64);          // row-sum over all 16 t
    float u = np * rcp_f(r);             // np for s=c is lane-local
    float w4[4];
    w4[0] = dpp_sum16(u * e0);
    w4[1] = dpp_sum16(u * e1);
    w4[2] = dpp_sum16(u * e2v);
    w4[3] = dpp_sum16(u * e3);           // w[t = 4g+i]  (VALU DPP)

    // ---------- vhat (prio-boosted cluster) + weighted readout ----------
    __builtin_amdgcn_s_setprio(1);
    #pragma unroll
    for (int n = 0; n < 4; ++n) {
      int eb = 16384 + (((n << 4) + c) << 6);
      int e7 = c & 7;
      f32x4 ar = {0.f,0.f,0.f,0.f}, ai = {0.f,0.f,0.f,0.f};
      #pragma unroll
      for (int t = 0; t < 2; ++t) {
        int ch = (((t << 2) + g) ^ e7) << 3;
        bf16x8 fr = *(const bf16x8*)&lds[eb + ch];
        bf16x8 fi = *(const bf16x8*)&lds[eb + 4096 + ch];
        ar = __builtin_amdgcn_mfma_f32_16x16x32_bf16(af[t],   fr, ar, 0,0,0);
        ai = __builtin_amdgcn_mfma_f32_16x16x32_bf16(af[t],   fi, ai, 0,0,0);
        ar = __builtin_amdgcn_mfma_f32_16x16x32_bf16(afn[t],  fi, ar, 0,0,0);
        ai = __builtin_amdgcn_mfma_f32_16x16x32_bf16(af[t+2], fr, ai, 0,0,0);
      }
      float prr = ar[0]*w4[0] + ar[1]*w4[1] + ar[2]*w4[2] + ar[3]*w4[3];
      float pri = ai[0]*w4[0] + ai[1]*w4[1] + ai[2]*w4[2] + ai[3]*w4[3];
      prr += __shfl_xor(prr, 16, 64);
      prr += __shfl_xor(prr, 32, 64);
      pri += __shfl_xor(pri, 16, 64);
      pri += __shfl_xor(pri, 32, 64);
      if (g == 0) out_zr[b*64 + (n << 4) + c] = prr;
      if (g == 1) out_zi[b*64 + (n << 4) + c] = pri;
    }
    __builtin_amdgcn_s_setprio(0);
  }

  // ---------- per-WG reduction of active-slot count, 1 atomic per WG ----------
  __syncthreads();                        // all SY use done
  unsigned int* cnt_lds = (unsigned int*)&lds[24576];
  if (tid == 0) *cnt_lds = 0u;
  __syncthreads();
  if (lane == 0) atomicAdd(cnt_lds, active_acc);
  __syncthreads();
  if (tid == 0) atomicAdd(ws_cnt, *cnt_lds);
}

extern "C" void kernel_launch(void* const* d_in, const int* in_sizes, int n_in,
                              void* d_out, int out_size, void* d_ws, size_t ws_size,
                              hipStream_t stream) {
  const float* z_real = (const float*)d_in[0];
  const float* z_imag = (const float*)d_in[1];
  const float* memp   = (const float*)d_in[2];
  const float* ptrv   = (const float*)d_in[3];
  const float* ctrl   = (const float*)d_in[4];
  const float* wq_r   = (const float*)d_in[5];
  const float* wq_i   = (const float*)d_in[6];
  const float* wk_r   = (const float*)d_in[7];
  const float* wk_i   = (const float*)d_in[8];
  const float* wv_r   = (const float*)d_in[9];
  const float* wv_i   = (const float*)d_in[10];

  float* out     = (float*)d_out;
  float* out_zr  = out;
  float* out_zi  = out + 2097152;
  float* out_mem = out + 4194304;
  float* out_ptr = out + 71303168;
  float* out_sc  = out + 71827456;

  unsigned int*   cnt = (unsigned int*)d_ws;
  unsigned short* mtp = (unsigned short*)((char*)d_ws + 1024);  // ws_size >= 33792

  ems_mt<<<128, 128, 0, stream>>>(wq_r, wq_i, wk_r, wk_i, mtp, cnt);
  ems_main<<<GRID_WG, 512, 0, stream>>>(z_real, z_imag, memp, ptrv, ctrl,
                                        wv_r, wv_i, mtp,
                                        out_zr, out_zi, out_mem, out_ptr, cnt);
  ems_fin<<<1, 64, 0, stream>>>(cnt, out_sc);
}